// Round 2
// baseline (283.792 us; speedup 1.0000x reference)
//
#include <hip/hip_runtime.h>

// Problem: out[b, x, y] = sum_k inputs[b,k] * W[y*82+x, k] + bias[y*82+x]
//   B=8192, F=64, P=5494 (NX=82, NY=67), out flat: b*5494 + x*67 + y
// Strategy: permute+convert W to bf16 once (Wp[c]=W[p(c)]), convert inputs to
// bf16, then row-major GEMM [8192,64]x[64,5504] with MFMA bf16.
// R2: nontemporal output stores (keep the 180 MB write stream out of L2 so the
// 1.7 MB of operands stay L2-resident for the direct-from-global fragment
// loads), fused convert kernel, guard-free epilogue fast path.

typedef __bf16 bf16x8 __attribute__((ext_vector_type(8)));
typedef float f32x4 __attribute__((ext_vector_type(4)));

#define B_DIM 8192
#define F_DIM 64
#define P_DIM 5494
#define PP_DIM 5504   // P padded to multiple of 128
#define NY_C 67

// round-to-nearest-even fp32 -> bf16
__device__ __forceinline__ unsigned short f2bf(float f) {
  unsigned int u = __float_as_uint(f);
  unsigned int r = u + 0x7fffu + ((u >> 16) & 1u);
  return (unsigned short)(r >> 16);
}

// Fused prep: blocks [0,512): convert A fp32->bf16 (4 elems/thread).
// blocks [512,856): permute+convert W, build permuted bias.
__global__ void prep_kernel(const float* __restrict__ A,
                            const float* __restrict__ W,
                            const float* __restrict__ bias,
                            unsigned short* __restrict__ Abf,
                            unsigned short* __restrict__ Wp,
                            float* __restrict__ bp) {
  if (blockIdx.x < 512) {
    int i = (blockIdx.x * 256 + threadIdx.x) * 4;
    float4 v = *(const float4*)(A + i);
    *(ushort4*)(Abf + i) = make_ushort4(f2bf(v.x), f2bf(v.y), f2bf(v.z), f2bf(v.w));
  } else {
    int t = (blockIdx.x - 512) * 256 + threadIdx.x;
    int c = t >> 4;          // Wp row (permuted pixel index), 16 threads/row
    int kq = (t & 15) * 4;   // k offset (4 floats)
    int x = c / NY_C;
    int y = c - x * NY_C;
    if (c < P_DIM) {
      int p = y * 82 + x;
      float4 v = *(const float4*)(W + p * 64 + kq);
      *(ushort4*)(Wp + c * 64 + kq) =
          make_ushort4(f2bf(v.x), f2bf(v.y), f2bf(v.z), f2bf(v.w));
      if (kq == 0) bp[c] = bias[p];
    } else {
      *(ushort4*)(Wp + c * 64 + kq) = make_ushort4(0, 0, 0, 0);
      if (kq == 0) bp[c] = 0.0f;
    }
  }
}

// GEMM: out[m][n] = Abf[m][:] . Wp[n][:] + bp[n]
// grid (43, 64): 128x128 tile per block, 4 waves 2x2, 64x64 per wave.
// K=64 -> 2 MFMAs (16x16x32) per 16x16 acc tile, 32 MFMAs/wave.
// Operands are L2-resident (1.7 MB total) -> fragments direct from global.
__global__ __launch_bounds__(256) void gemm_kernel(
    const unsigned short* __restrict__ Abf,
    const unsigned short* __restrict__ Wp,
    const float* __restrict__ bp,
    float* __restrict__ out) {
  const int tid = threadIdx.x;
  const int wid = tid >> 6;
  const int lane = tid & 63;
  const int quad = lane >> 4;
  const int l16 = lane & 15;
  const int wm = (wid >> 1) * 64;   // wave row offset in 128-tile
  const int wn = (wid & 1) * 64;    // wave col offset
  const int m0 = blockIdx.y * 128 + wm;
  const int n0 = blockIdx.x * 128 + wn;

  // A-op layout: lane holds A[m = l16][k = quad*8 + j], j=0..7
  // B-op layout: lane holds B^T[n = l16][k = quad*8 + j]  (Wp row-major [n][k])
  bf16x8 a_frag[4][2], b_frag[4][2];
#pragma unroll
  for (int i = 0; i < 4; ++i) {
#pragma unroll
    for (int kb = 0; kb < 2; ++kb) {
      a_frag[i][kb] = *(const bf16x8*)(Abf + (size_t)(m0 + i * 16 + l16) * 64 +
                                       kb * 32 + quad * 8);
      b_frag[i][kb] = *(const bf16x8*)(Wp + (size_t)(n0 + i * 16 + l16) * 64 +
                                       kb * 32 + quad * 8);
    }
  }

  f32x4 acc[4][4];
#pragma unroll
  for (int mi = 0; mi < 4; ++mi) {
#pragma unroll
    for (int ni = 0; ni < 4; ++ni) {
      f32x4 c = {0.0f, 0.0f, 0.0f, 0.0f};
      c = __builtin_amdgcn_mfma_f32_16x16x32_bf16(a_frag[mi][0], b_frag[ni][0], c, 0, 0, 0);
      c = __builtin_amdgcn_mfma_f32_16x16x32_bf16(a_frag[mi][1], b_frag[ni][1], c, 0, 0, 0);
      acc[mi][ni] = c;
    }
  }

  // Epilogue. C/D layout: col = l16, row = quad*4 + r.
  float biasv[4];
  int colv[4];
#pragma unroll
  for (int ni = 0; ni < 4; ++ni) {
    colv[ni] = n0 + ni * 16 + l16;
    biasv[ni] = (colv[ni] < P_DIM) ? bp[colv[ni]] : 0.0f;
  }

  if (n0 + 63 < P_DIM) {
    // Fast path: whole wave tile in-bounds, no guards. Nontemporal stores keep
    // the write-once stream out of L2 (operands must stay resident).
#pragma unroll
    for (int mi = 0; mi < 4; ++mi) {
#pragma unroll
      for (int r = 0; r < 4; ++r) {
        const int row = m0 + mi * 16 + quad * 4 + r;
        float* rp = out + (size_t)row * P_DIM;
#pragma unroll
        for (int ni = 0; ni < 4; ++ni) {
          __builtin_nontemporal_store(acc[mi][ni][r] + biasv[ni], rp + colv[ni]);
        }
      }
    }
  } else {
#pragma unroll
    for (int mi = 0; mi < 4; ++mi) {
#pragma unroll
      for (int r = 0; r < 4; ++r) {
        const int row = m0 + mi * 16 + quad * 4 + r;
        float* rp = out + (size_t)row * P_DIM;
#pragma unroll
        for (int ni = 0; ni < 4; ++ni) {
          if (colv[ni] < P_DIM)
            __builtin_nontemporal_store(acc[mi][ni][r] + biasv[ni], rp + colv[ni]);
        }
      }
    }
  }
}

extern "C" void kernel_launch(void* const* d_in, const int* in_sizes, int n_in,
                              void* d_out, int out_size, void* d_ws, size_t ws_size,
                              hipStream_t stream) {
  (void)in_sizes; (void)n_in; (void)out_size; (void)ws_size;
  const float* A = (const float*)d_in[0];      // [8192, 64]
  const float* W = (const float*)d_in[1];      // [5494, 64]
  const float* bias = (const float*)d_in[2];   // [5494]
  float* out = (float*)d_out;                  // [8192, 82, 67, 1] contiguous

  // workspace layout (~1.8 MB)
  unsigned short* Abf = (unsigned short*)d_ws;                       // 1 MB
  unsigned short* Wp = (unsigned short*)((char*)d_ws + 1048576);     // 704512 B
  float* bp = (float*)((char*)d_ws + 1048576 + 704512);              // 22016 B

  prep_kernel<<<856, 256, 0, stream>>>(A, W, bias, Abf, Wp, bp);
  gemm_kernel<<<dim3(PP_DIM / 128, B_DIM / 128), 256, 0, stream>>>(Abf, Wp, bp, out);
}

// Round 3
// 203.221 us; speedup vs baseline: 1.3965x; 1.3965x over previous
//
#include <hip/hip_runtime.h>

// Problem: out[b, x, y] = sum_k inputs[b,k] * W[y*82+x, k] + bias[y*82+x]
//   B=8192, F=64, P=5494 (NX=82, NY=67), out flat: b*5494 + x*67 + y
// Strategy: permute+convert W to bf16 (Wp[c]=W[p(c)]), convert A to bf16,
// row-major MFMA-bf16 GEMM [8192,64]x[64,5504]. Operands (1.7 MB) stay
// L2-resident; fragments load directly from global.
// R3: reverted nontemporal stores (R2 showed 1.5x write amplification, 274 MB
// vs 180 MB ideal — nt bypassed L2 write-combining of our scattered 4-B
// stores). Epilogue now transposes each wave's 16x64 acc tile through
// wave-private LDS and stores dwordx4 (256 B contiguous per 16-lane row-run).

typedef __bf16 bf16x8 __attribute__((ext_vector_type(8)));
typedef float f32x4 __attribute__((ext_vector_type(4)));
typedef float f32x4u __attribute__((ext_vector_type(4), aligned(4)));

#define B_DIM 8192
#define F_DIM 64
#define P_DIM 5494
#define PP_DIM 5504   // P padded to multiple of 128
#define NY_C 67

// round-to-nearest-even fp32 -> bf16
__device__ __forceinline__ unsigned short f2bf(float f) {
  unsigned int u = __float_as_uint(f);
  unsigned int r = u + 0x7fffu + ((u >> 16) & 1u);
  return (unsigned short)(r >> 16);
}

// Fused prep: blocks [0,512): convert A fp32->bf16 (4 elems/thread).
// blocks [512,856): permute+convert W, build permuted (zero-padded) bias.
__global__ void prep_kernel(const float* __restrict__ A,
                            const float* __restrict__ W,
                            const float* __restrict__ bias,
                            unsigned short* __restrict__ Abf,
                            unsigned short* __restrict__ Wp,
                            float* __restrict__ bp) {
  if (blockIdx.x < 512) {
    int i = (blockIdx.x * 256 + threadIdx.x) * 4;
    float4 v = *(const float4*)(A + i);
    *(ushort4*)(Abf + i) = make_ushort4(f2bf(v.x), f2bf(v.y), f2bf(v.z), f2bf(v.w));
  } else {
    int t = (blockIdx.x - 512) * 256 + threadIdx.x;
    int c = t >> 4;          // Wp row (permuted pixel index), 16 threads/row
    int kq = (t & 15) * 4;   // k offset (4 floats)
    int x = c / NY_C;
    int y = c - x * NY_C;
    if (c < P_DIM) {
      int p = y * 82 + x;
      float4 v = *(const float4*)(W + p * 64 + kq);
      *(ushort4*)(Wp + c * 64 + kq) =
          make_ushort4(f2bf(v.x), f2bf(v.y), f2bf(v.z), f2bf(v.w));
      if (kq == 0) bp[c] = bias[p];
    } else {
      *(ushort4*)(Wp + c * 64 + kq) = make_ushort4(0, 0, 0, 0);
      if (kq == 0) bp[c] = 0.0f;
    }
  }
}

// GEMM: out[m][n] = Abf[m][:] . Wp[n][:] + bp[n]
// grid (43, 64): 128x128 tile per block, 4 waves 2x2, 64x64 per wave.
// K=64 -> 2 MFMAs (16x16x32) per 16x16 acc tile.
__global__ __launch_bounds__(256) void gemm_kernel(
    const unsigned short* __restrict__ Abf,
    const unsigned short* __restrict__ Wp,
    const float* __restrict__ bp,
    float* __restrict__ out) {
  const int tid = threadIdx.x;
  const int wid = tid >> 6;
  const int lane = tid & 63;
  const int quad = lane >> 4;
  const int l16 = lane & 15;
  const int wm = (wid >> 1) * 64;   // wave row offset in 128-tile
  const int wn = (wid & 1) * 64;    // wave col offset
  const int m0 = blockIdx.y * 128 + wm;
  const int n0 = blockIdx.x * 128 + wn;

  // Wave-private transpose buffers: [16 rows][68 cols] (+4-word pad -> <=2-way
  // bank conflicts both directions, 272 B row stride keeps 16 B alignment).
  __shared__ float lds[4][16][68];

  // A-op layout: lane holds A[m = l16][k = quad*8 + j], j=0..7
  // B-op layout: lane holds B^T[n = l16][k = quad*8 + j]  (Wp row-major [n][k])
  bf16x8 a_frag[4][2], b_frag[4][2];
#pragma unroll
  for (int i = 0; i < 4; ++i) {
#pragma unroll
    for (int kb = 0; kb < 2; ++kb) {
      a_frag[i][kb] = *(const bf16x8*)(Abf + (size_t)(m0 + i * 16 + l16) * 64 +
                                       kb * 32 + quad * 8);
      b_frag[i][kb] = *(const bf16x8*)(Wp + (size_t)(n0 + i * 16 + l16) * 64 +
                                       kb * 32 + quad * 8);
    }
  }

  f32x4 acc[4][4];
#pragma unroll
  for (int mi = 0; mi < 4; ++mi) {
#pragma unroll
    for (int ni = 0; ni < 4; ++ni) {
      f32x4 c = {0.0f, 0.0f, 0.0f, 0.0f};
      c = __builtin_amdgcn_mfma_f32_16x16x32_bf16(a_frag[mi][0], b_frag[ni][0], c, 0, 0, 0);
      c = __builtin_amdgcn_mfma_f32_16x16x32_bf16(a_frag[mi][1], b_frag[ni][1], c, 0, 0, 0);
      acc[mi][ni] = c;
    }
  }

  // Bias per pre-transpose column (bp is zero-padded to 5504 -> no guard).
  float biasv[4];
#pragma unroll
  for (int ni = 0; ni < 4; ++ni) biasv[ni] = bp[n0 + ni * 16 + l16];

  const bool fastn = (n0 + 63 < P_DIM);  // whole 64-col wave tile in-bounds

  // Epilogue: per 16x64 acc slice (mi), stage to LDS in C/D layout
  // (row = quad*4+r, col = ni*16+l16), read back 4 consecutive cols per lane,
  // store dwordx4 (lanes 0-15 = 256 B contiguous per row).
#pragma unroll
  for (int mi = 0; mi < 4; ++mi) {
#pragma unroll
    for (int ni = 0; ni < 4; ++ni)
#pragma unroll
      for (int r = 0; r < 4; ++r)
        lds[wid][quad * 4 + r][ni * 16 + l16] = acc[mi][ni][r] + biasv[ni];
    // wave-private buffer: no __syncthreads needed; compiler inserts lgkmcnt
#pragma unroll
    for (int j = 0; j < 4; ++j) {
      const int row_l = 4 * j + (lane >> 4);
      const int c4 = 4 * (lane & 15);
      f32x4 v = *(const f32x4*)&lds[wid][row_l][c4];
      const int grow = m0 + mi * 16 + row_l;
      const int gcol = n0 + c4;
      float* p = out + (size_t)grow * P_DIM + gcol;
      if (fastn) {
        *(f32x4u*)p = v;
      } else {
#pragma unroll
        for (int e = 0; e < 4; ++e)
          if (gcol + e < P_DIM) p[e] = v[e];
      }
    }
  }
}

extern "C" void kernel_launch(void* const* d_in, const int* in_sizes, int n_in,
                              void* d_out, int out_size, void* d_ws, size_t ws_size,
                              hipStream_t stream) {
  (void)in_sizes; (void)n_in; (void)out_size; (void)ws_size;
  const float* A = (const float*)d_in[0];      // [8192, 64]
  const float* W = (const float*)d_in[1];      // [5494, 64]
  const float* bias = (const float*)d_in[2];   // [5494]
  float* out = (float*)d_out;                  // [8192, 82, 67, 1] contiguous

  // workspace layout (~1.8 MB)
  unsigned short* Abf = (unsigned short*)d_ws;                       // 1 MB
  unsigned short* Wp = (unsigned short*)((char*)d_ws + 1048576);     // 704512 B
  float* bp = (float*)((char*)d_ws + 1048576 + 704512);              // 22016 B

  prep_kernel<<<856, 256, 0, stream>>>(A, W, bias, Abf, Wp, bp);
  gemm_kernel<<<dim3(PP_DIM / 128, B_DIM / 128), 256, 0, stream>>>(Abf, Wp, bp, out);
}